// Round 17
// baseline (1245.493 us; speedup 1.0000x reference)
//
#include <hip/hip_runtime.h>
#include <hip/hip_bf16.h>

#define NN 50000
#define NE 800000
#define ROWB 272   // edge LDS row stride: 128 bf16 + 8 pad
#define NROWB 528  // node LDS row stride: 256 bf16 + 8 pad

typedef unsigned short u16;
typedef unsigned int u32;
typedef __attribute__((ext_vector_type(4))) float f32x4;
typedef __attribute__((ext_vector_type(8))) short short8;

// ws layout:
//   u16 wt[147456]   @0        : w1t(K=384) w2t@49152 w3t@65536 n1t@81920(K=256) n2t@114688 n3t@131072 ([n][k], bf16)
//   f32 stats[512]   @294912
//   int cnt[50000]   @297216
//   int off[50001]   @497408
//   int cursor[50000]@697600
//   int perm[800000] @897792   (fallback only)
//   int rank[800000] @4097792
//   u16 oBuf[NE*128] @7297792           (useO: ws >= 212.1 MB)
//   u16 xB[NN*128]   @212097792         (useX: ws >= 224.9 MB)
// d_out aliasing: Pab (u16[NN*256]) in outX slot during edge; node overwrites; pairnorm finalizes.

__device__ __forceinline__ u16 f2b(float f){ __hip_bfloat16 h = __float2bfloat16(f); u16 u; __builtin_memcpy(&u, &h, 2); return u; }
__device__ __forceinline__ float b2f(u16 u){ __hip_bfloat16 h; __builtin_memcpy(&h, &u, 2); return __bfloat162float(h); }
__device__ __forceinline__ float siluf(float v){
  const float e = __expf(-v);
  return v * __builtin_amdgcn_rcpf(1.f + e);
}

__device__ __forceinline__ uint4 cvt8(const float* __restrict__ s){
  const float4 a = *(const float4*)s;
  const float4 b = *(const float4*)(s + 4);
  union { u16 h[8]; uint4 q; } u;
  u.h[0]=f2b(a.x); u.h[1]=f2b(a.y); u.h[2]=f2b(a.z); u.h[3]=f2b(a.w);
  u.h[4]=f2b(b.x); u.h[5]=f2b(b.y); u.h[6]=f2b(b.z); u.h[7]=f2b(b.w);
  return u.q;
}

// --- row-band GEMM: one wave owns 16 rows x 128 output cols; K=128 per call ---
// bandA points at the wave's row-0; ldsb = LDS row stride in bytes.
// Weights wB: bf16 [n][Kw] (L2-resident), reads k in [0,128).
template<int Kw>
__device__ __forceinline__ void gemm_band(f32x4 acc[8], const char* bandA, int ldsb,
                                          const u16* __restrict__ wB, int l15, int l4){
  #pragma unroll
  for (int ks = 0; ks < 4; ++ks){
    const short8 a = *(const short8*)(bandA + l15*ldsb + ks*64 + l4*16);
    #pragma unroll
    for (int fc = 0; fc < 8; ++fc){
      const short8 b = *(const short8*)(wB + (size_t)(fc*16 + l15)*Kw + ks*32 + l4*8);
      acc[fc] = __builtin_amdgcn_mfma_f32_16x16x32_bf16(a, b, acc[fc], 0, 0, 0);
    }
  }
}

// acc + bias [+SiLU] -> bf16 into the wave's own band. C/D: col=l15, row=l4*4+j.
__device__ __forceinline__ void epi_band(const f32x4 acc[8], const float* __restrict__ bias,
                                         char* band, int ldsb, int l15, int l4, bool doSilu){
  #pragma unroll
  for (int fc = 0; fc < 8; ++fc){
    const int col = fc*16 + l15;
    const float bv = bias[col];
    #pragma unroll
    for (int j = 0; j < 4; ++j){
      float v = acc[fc][j] + bv;
      if (doSilu) v = siluf(v);
      *(u16*)(band + (l4*4 + j)*ldsb + col*2) = f2b(v);
    }
  }
}

// 64-row tile, 4 waves (for Pab precompute): wm=wid>>1, wn=wid&1. acc[2][4].
template<int K>
__device__ __forceinline__ void gemm64(f32x4 acc[2][4], const u16* __restrict__ sA,
                                       const u16* __restrict__ wB, int wm, int wn, int lane){
  const int l15 = lane & 15, l4 = lane >> 4;
  const u16* w0 = wB + (size_t)(wn*64 + l15)*K + l4*8;
  #pragma unroll
  for (int ks = 0; ks < 4; ++ks){
    short8 b[4];
    #pragma unroll
    for (int fc = 0; fc < 4; ++fc)
      b[fc] = *(const short8*)(w0 + (size_t)fc*16*K + ks*32);
    const int kb = ks*64 + l4*16;
    short8 a[2];
    #pragma unroll
    for (int fr = 0; fr < 2; ++fr)
      a[fr] = *(const short8*)((const char*)sA + (wm*32 + fr*16 + l15)*ROWB + kb);
    #pragma unroll
    for (int fr = 0; fr < 2; ++fr)
      #pragma unroll
      for (int fc = 0; fc < 4; ++fc)
        acc[fr][fc] = __builtin_amdgcn_mfma_f32_16x16x32_bf16(a[fr], b[fc], acc[fr][fc], 0, 0, 0);
  }
}

// fused: weight transpose + x->bf16 + receiver count (rank saved for slot assignment)
__global__ __launch_bounds__(256) void prep_kernel(const float* __restrict__ w1, const float* __restrict__ w2,
                                                   const float* __restrict__ w3, const float* __restrict__ m1,
                                                   const float* __restrict__ m2, const float* __restrict__ m3,
                                                   u16* __restrict__ wt,
                                                   const float* __restrict__ x, u16* __restrict__ xB,
                                                   const int* __restrict__ eidx, int* __restrict__ cnt,
                                                   int* __restrict__ rank){
  const int i = blockIdx.x * 256 + threadIdx.x;     // 0 .. 799999
  if (i < 147456){
    const float* src; int K, base, off;
    if      (i < 49152)  { src = w1; K = 384; base = 0;      off = i; }
    else if (i < 65536)  { src = w2; K = 128; base = 49152;  off = i - 49152; }
    else if (i < 81920)  { src = w3; K = 128; base = 65536;  off = i - 65536; }
    else if (i < 114688) { src = m1; K = 256; base = 81920;  off = i - 81920; }
    else if (i < 131072) { src = m2; K = 128; base = 114688; off = i - 114688; }
    else                 { src = m3; K = 128; base = 131072; off = i - 131072; }
    const int k = off >> 7, n = off & 127;
    wt[base + n*K + k] = f2b(src[off]);
  }
  if (xB){
    const size_t o = (size_t)i * 8;
    *(uint4*)(xB + o) = cvt8(x + o);
  }
  rank[i] = atomicAdd(&cnt[eidx[NE + i]], 1);
}

// fallback-only scatter (perm for agg_f)
__global__ __launch_bounds__(256) void scatter_kernel(const int* __restrict__ eidx, int* __restrict__ cursor,
                                                      int* __restrict__ perm){
  const int i = blockIdx.x * 256 + threadIdx.x;
  if (i < NE){
    const int pos = atomicAdd(&cursor[eidx[NE + i]], 1);
    perm[pos] = i;
  }
}

// ---------------- fused: block 0 = CSR scan; blocks 1..782 = Pab precompute ----------------
__global__ __launch_bounds__(256, 4) void scanpre_kernel(const int* __restrict__ cnt, int* __restrict__ off,
                                                         int* __restrict__ cursor,
                                                         const float* __restrict__ x, const u16* __restrict__ xB,
                                                         const u16* __restrict__ wt, u16* __restrict__ Pab){
  const int t = threadIdx.x;
  if (blockIdx.x == 0){
    __shared__ int s[256];
    const int CH = 196;
    int sum = 0;
    for (int i = 0; i < CH; ++i){
      const int idx = t*CH + i;
      if (idx < NN) sum += cnt[idx];
    }
    s[t] = sum;
    __syncthreads();
    for (int d = 1; d < 256; d <<= 1){
      int v = (t >= d) ? s[t - d] : 0;
      __syncthreads();
      s[t] += v;
      __syncthreads();
    }
    int run = s[t] - sum;
    for (int i = 0; i < CH; ++i){
      const int idx = t*CH + i;
      if (idx < NN){
        off[idx] = run;
        cursor[idx] = run;
        run += cnt[idx];
        if (idx == NN - 1) off[NN] = run;
      }
    }
    return;
  }

  __shared__ u16 sX[64*136];
  const int nBase = (blockIdx.x - 1) * 64;
  const int lane = t & 63, wid = t >> 6;
  const int wm = wid >> 1, wn = wid & 1;
  const int chunk = t & 15, r0 = t >> 4;

  #pragma unroll
  for (int p = 0; p < 4; ++p){
    const int row = r0 + p*16;
    const int node = nBase + row;
    uint4 v = {0u, 0u, 0u, 0u};
    if (node < NN){
      if (xB) v = *(const uint4*)(xB + (size_t)node*128 + chunk*8);
      else    v = cvt8(x + (size_t)node*128 + chunk*8);
    }
    *(uint4*)((char*)sX + row*ROWB + chunk*16) = v;
  }
  __syncthreads();

  const f32x4 z4 = {0.f, 0.f, 0.f, 0.f};
  const int l15 = lane & 15, l4 = lane >> 4;
  #pragma unroll
  for (int half = 0; half < 2; ++half){
    f32x4 acc[2][4];
    #pragma unroll
    for (int fr = 0; fr < 2; ++fr)
      #pragma unroll
      for (int fc = 0; fc < 4; ++fc) acc[fr][fc] = z4;
    gemm64<384>(acc, sX, wt + half*128, wm, wn, lane);
    #pragma unroll
    for (int fc = 0; fc < 4; ++fc){
      const int col = wn*64 + fc*16 + l15;
      #pragma unroll
      for (int fr = 0; fr < 2; ++fr){
        const int rbase = wm*32 + fr*16 + l4*4;
        #pragma unroll
        for (int j = 0; j < 4; ++j){
          const int node = nBase + rbase + j;
          if (node < NN) Pab[(size_t)node*256 + half*128 + col] = f2b(acc[fr][fc][j]);
        }
      }
    }
  }
}

// ---------------- edge: row-band per wave, ONE barrier ----------------
__global__ __launch_bounds__(512, 4) void edge_kernel(
    const float* __restrict__ ea, const int* __restrict__ eidx,
    const u16* __restrict__ wt, const u16* __restrict__ Pab,
    const float* __restrict__ b1, const float* __restrict__ b2,
    const float* __restrict__ b3, const float* __restrict__ gma, const float* __restrict__ bta,
    const int* __restrict__ off, const int* __restrict__ rank,
    float* __restrict__ outE, u16* __restrict__ oBuf)
{
  __shared__ u16 sA[128*136];
  __shared__ float sMeta[640];
  __shared__ int sIdx[256];
  __shared__ int sSlot[128];
  const int t = threadIdx.x;
  const size_t eBase = (size_t)blockIdx.x * 128;

  if (t < 128){
    sIdx[t] = eidx[eBase + t];
    const int r = eidx[(size_t)NE + eBase + t];
    sIdx[t + 128] = r;
    sSlot[t] = oBuf ? (off[r] + rank[eBase + t]) : 0;
    sMeta[t]       = b1[t];
    sMeta[t + 128] = b2[t];
    sMeta[t + 256] = b3[t];
    sMeta[t + 384] = gma[t];
    sMeta[t + 512] = bta[t];
  }
  __syncthreads();   // the only block-wide barrier

  const int lane = t & 63, wid = t >> 6;
  const int l15 = lane & 15, l4 = lane >> 4;
  const int rowL = lane >> 2, cg = lane & 3;         // staging/LN mapping (wave-private rows)
  char* band = (char*)sA + wid*16*ROWB;
  const int rowBlk = wid*16 + rowL;                   // block-local row 0..127

  // stage ea into own band (keep bf16 quads for residual)
  uint4 eaQ[4];
  const float* eaRow = ea + (eBase + rowBlk)*128 + cg*32;
  #pragma unroll
  for (int q = 0; q < 4; ++q){
    eaQ[q] = cvt8(eaRow + q*8);
    *(uint4*)(band + rowL*ROWB + cg*64 + q*16) = eaQ[q];
  }

  // seed acc from global Pab at this lane's C/D coordinates
  f32x4 acc[8];
  #pragma unroll
  for (int fc = 0; fc < 8; ++fc){
    const int col = fc*16 + l15;
    #pragma unroll
    for (int j = 0; j < 4; ++j){
      const int r = wid*16 + l4*4 + j;
      acc[fc][j] = b2f(Pab[(size_t)sIdx[r]*256 + col]) +
                   b2f(Pab[(size_t)sIdx[r + 128]*256 + 128 + col]);
    }
  }

  const f32x4 z4 = {0.f, 0.f, 0.f, 0.f};
  gemm_band<384>(acc, band, ROWB, wt + 256, l15, l4);        // + ea @ W1c
  epi_band(acc, sMeta + 0, band, ROWB, l15, l4, true);        // h1
  #pragma unroll
  for (int fc = 0; fc < 8; ++fc) acc[fc] = z4;
  gemm_band<128>(acc, band, ROWB, wt + 49152, l15, l4);       // h1 @ W2
  epi_band(acc, sMeta + 128, band, ROWB, l15, l4, true);      // h2
  #pragma unroll
  for (int fc = 0; fc < 8; ++fc) acc[fc] = z4;
  gemm_band<128>(acc, band, ROWB, wt + 65536, l15, l4);       // h2 @ W3
  epi_band(acc, sMeta + 256, band, ROWB, l15, l4, false);     // h3

  // LayerNorm (3-pass over own band row) + residual + oBuf
  const char* myRow = band + rowL*ROWB + cg*64;
  float s = 0.f;
  #pragma unroll
  for (int q = 0; q < 4; ++q){
    uint4 qv = *(const uint4*)(myRow + q*16);
    const u16* pu = (const u16*)&qv;
    #pragma unroll
    for (int j = 0; j < 8; ++j) s += b2f(pu[j]);
  }
  s += __shfl_xor(s, 1); s += __shfl_xor(s, 2);
  const float mu = s * (1.f/128.f);
  float ss = 0.f;
  #pragma unroll
  for (int q = 0; q < 4; ++q){
    uint4 qv = *(const uint4*)(myRow + q*16);
    const u16* pu = (const u16*)&qv;
    #pragma unroll
    for (int j = 0; j < 8; ++j){ const float d = b2f(pu[j]) - mu; ss += d*d; }
  }
  ss += __shfl_xor(ss, 1); ss += __shfl_xor(ss, 2);
  const float rs = rsqrtf(fmaxf(ss*(1.f/128.f), 0.f) + 1e-5f);
  const size_t e = eBase + rowBlk;
  float* dst = outE + e*128 + cg*32;
  u16* od = oBuf ? (oBuf + (size_t)sSlot[rowBlk]*128 + cg*32) : (u16*)nullptr;
  #pragma unroll
  for (int q = 0; q < 4; ++q){
    uint4 qv = *(const uint4*)(myRow + q*16);
    const u16* pu = (const u16*)&qv;
    const u16* ep = (const u16*)&eaQ[q];
    alignas(16) float orow[8];
    alignas(16) u16 obf[8];
    #pragma unroll
    for (int j = 0; j < 8; ++j){
      const int col = cg*32 + q*8 + j;
      const float o = sMeta[384 + col]*(b2f(pu[j]) - mu)*rs + sMeta[512 + col];
      orow[j] = b2f(ep[j]) + o;
      obf[j] = f2b(o);
    }
    *(float4*)(dst + q*8)     = ((const float4*)orow)[0];
    *(float4*)(dst + q*8 + 4) = ((const float4*)orow)[1];
    if (od) *(uint4*)(od + q*8) = *(const uint4*)obf;
  }
}

// ---------------- fallback aggregation ----------------
__global__ __launch_bounds__(256) void agg_f_kernel(const float* __restrict__ outE, const float* __restrict__ ea,
                                                    const int* __restrict__ off, const int* __restrict__ perm,
                                                    float* __restrict__ agg){
  const int node = blockIdx.x * 4 + (threadIdx.x >> 6);
  const int lane = threadIdx.x & 63;
  if (node >= NN) return;
  const int s = off[node], e = off[node + 1];
  float a0 = 0.f, a1 = 0.f;
  for (int i = s; i < e; ++i){
    const size_t r = (size_t)perm[i] * 128;
    a0 += outE[r + lane]      - ea[r + lane];
    a1 += outE[r + 64 + lane] - ea[r + 64 + lane];
  }
  agg[(size_t)node*128 + lane]      = a0;
  agg[(size_t)node*128 + 64 + lane] = a1;
}

// ---------------- node: row-band per wave (64 nodes, 4 waves), 2 barriers ----------------
__global__ __launch_bounds__(256, 4) void node_kernel(
    const float* __restrict__ x, const float* __restrict__ aggF,
    const u16* __restrict__ oBuf, const int* __restrict__ off,
    const u16* __restrict__ wt,
    const float* __restrict__ b1, const float* __restrict__ b2, const float* __restrict__ b3,
    const float* __restrict__ gma, const float* __restrict__ bta,
    float* __restrict__ outX, float* __restrict__ stats)
{
  __shared__ u16 sN[64*264];   // 64 rows x 264 u16 (K=256 + pad)
  __shared__ float sMeta[640];
  __shared__ float sCol[128];
  __shared__ float sSq;
  const int t = threadIdx.x;
  const int nBase = blockIdx.x * 64;

  if (t < 128){
    sMeta[t]       = b1[t];
    sMeta[t + 128] = b2[t];
    sMeta[t + 256] = b3[t];
    sMeta[t + 384] = gma[t];
    sMeta[t + 512] = bta[t];
    sCol[t] = 0.f;
  }
  if (t == 0) sSq = 0.f;
  __syncthreads();

  const int lane = t & 63, wid = t >> 6;
  const int l15 = lane & 15, l4 = lane >> 4;
  const int rowL = lane >> 2, cg = lane & 3;
  char* band = (char*)sN + wid*16*NROWB;
  const int node = nBase + wid*16 + rowL;

  // stage x (k 0..127) and agg (k 128..255) into own band
  {
    #pragma unroll
    for (int q = 0; q < 4; ++q){
      uint4 v = {0u,0u,0u,0u};
      if (node < NN) v = cvt8(x + (size_t)node*128 + cg*32 + q*8);
      *(uint4*)(band + rowL*NROWB + cg*64 + q*16) = v;
    }
    if (node < NN && oBuf){
      float a32[32];
      #pragma unroll
      for (int j = 0; j < 32; ++j) a32[j] = 0.f;
      const int s0 = off[node], e0 = off[node + 1];
      for (int i = s0; i < e0; ++i){
        const u16* src = oBuf + (size_t)i*128 + cg*32;
        #pragma unroll
        for (int q = 0; q < 4; ++q){
          uint4 qv = *(const uint4*)(src + q*8);
          const u16* pu = (const u16*)&qv;
          #pragma unroll
          for (int j = 0; j < 8; ++j) a32[q*8 + j] += b2f(pu[j]);
        }
      }
      #pragma unroll
      for (int q = 0; q < 4; ++q){
        union { u16 h[8]; uint4 qq; } u;
        #pragma unroll
        for (int j = 0; j < 8; ++j) u.h[j] = f2b(a32[q*8 + j]);
        *(uint4*)(band + rowL*NROWB + 256 + cg*64 + q*16) = u.qq;
      }
    } else {
      #pragma unroll
      for (int q = 0; q < 4; ++q){
        uint4 v = {0u,0u,0u,0u};
        if (node < NN) v = cvt8(aggF + (size_t)node*128 + cg*32 + q*8);
        *(uint4*)(band + rowL*NROWB + 256 + cg*64 + q*16) = v;
      }
    }
  }

  const f32x4 z4 = {0.f, 0.f, 0.f, 0.f};
  f32x4 acc[8];
  #pragma unroll
  for (int fc = 0; fc < 8; ++fc) acc[fc] = z4;
  gemm_band<256>(acc, band, NROWB, wt + 81920, l15, l4);         // k 0..127
  gemm_band<256>(acc, band + 256, NROWB, wt + 81920 + 128, l15, l4); // k 128..255
  epi_band(acc, sMeta + 0, band, NROWB, l15, l4, true);
  #pragma unroll
  for (int fc = 0; fc < 8; ++fc) acc[fc] = z4;
  gemm_band<128>(acc, band, NROWB, wt + 114688, l15, l4);
  epi_band(acc, sMeta + 128, band, NROWB, l15, l4, true);
  #pragma unroll
  for (int fc = 0; fc < 8; ++fc) acc[fc] = z4;
  gemm_band<128>(acc, band, NROWB, wt + 131072, l15, l4);
  epi_band(acc, sMeta + 256, band, NROWB, l15, l4, false);

  // LN + residual + pairnorm stats (3-pass over own band row)
  {
    const char* myRow = band + rowL*NROWB + cg*64;
    float s = 0.f;
    #pragma unroll
    for (int q = 0; q < 4; ++q){
      uint4 qv = *(const uint4*)(myRow + q*16);
      const u16* pu = (const u16*)&qv;
      #pragma unroll
      for (int j = 0; j < 8; ++j) s += b2f(pu[j]);
    }
    s += __shfl_xor(s, 1); s += __shfl_xor(s, 2);
    const float mu = s * (1.f/128.f);
    float ss = 0.f;
    #pragma unroll
    for (int q = 0; q < 4; ++q){
      uint4 qv = *(const uint4*)(myRow + q*16);
      const u16* pu = (const u16*)&qv;
      #pragma unroll
      for (int j = 0; j < 8; ++j){ const float d = b2f(pu[j]) - mu; ss += d*d; }
    }
    ss += __shfl_xor(ss, 1); ss += __shfl_xor(ss, 2);
    const float rs = rsqrtf(fmaxf(ss*(1.f/128.f), 0.f) + 1e-5f);
    float lssq = 0.f;
    if (node < NN){
      float* dst = outX + (size_t)node*128 + cg*32;
      const float* xRow = x + (size_t)node*128 + cg*32;
      #pragma unroll
      for (int q = 0; q < 4; ++q){
        uint4 qv = *(const uint4*)(myRow + q*16);
        const u16* pu = (const u16*)&qv;
        const float4 xa = *(const float4*)(xRow + q*8);
        const float4 xb = *(const float4*)(xRow + q*8 + 4);
        const float xr[8] = {xa.x, xa.y, xa.z, xa.w, xb.x, xb.y, xb.z, xb.w};
        alignas(16) float orow[8];
        #pragma unroll
        for (int j = 0; j < 8; ++j){
          const int col = cg*32 + q*8 + j;
          const float o = sMeta[384 + col]*(b2f(pu[j]) - mu)*rs + sMeta[512 + col];
          const float res = xr[j] + o;   // RESIDUAL_SCALE = 1
          orow[j] = res;
          atomicAdd(&sCol[col], res);
          lssq += res*res;
        }
        *(float4*)(dst + q*8)     = ((const float4*)orow)[0];
        *(float4*)(dst + q*8 + 4) = ((const float4*)orow)[1];
      }
    }
    #pragma unroll
    for (int m = 1; m < 64; m <<= 1) lssq += __shfl_xor(lssq, m);
    if (lane == 0) atomicAdd(&sSq, lssq);
  }
  __syncthreads();
  if (t < 128) atomicAdd(&stats[t], sCol[t]);
  if (t == 0)  atomicAdd(&stats[128], sSq);
}

// ---------------- pairnorm (finalize fused) ----------------
__global__ __launch_bounds__(256) void pairnorm_kernel(float* __restrict__ xOut, const float* __restrict__ stats){
  __shared__ float sMean[128];
  __shared__ float sP2[2];
  __shared__ float sInv;
  const int t = threadIdx.x;
  float m2 = 0.f;
  if (t < 128){
    const float mean = stats[t] * (1.f / (float)NN);
    sMean[t] = mean;
    m2 = mean * mean;
  }
  #pragma unroll
  for (int m = 1; m < 64; m <<= 1) m2 += __shfl_xor(m2, m);
  if ((t & 63) == 0 && t < 128) sP2[t >> 6] = m2;
  __syncthreads();
  if (t == 0){
    float ssc = stats[128] - (float)NN * (sP2[0] + sP2[1]);
    ssc = fmaxf(ssc, 0.f);
    const float rms = sqrtf(ssc * (1.f / (float)NN)) + 1e-8f;
    sInv = 1.f / rms;
  }
  __syncthreads();
  const size_t base = ((size_t)blockIdx.x * 256 + t) * 4;
  const int col = (int)(base & 127);
  float4 q = *(float4*)(xOut + base);
  const float inv = sInv;
  q.x = (q.x - sMean[col])     * inv;
  q.y = (q.y - sMean[col + 1]) * inv;
  q.z = (q.z - sMean[col + 2]) * inv;
  q.w = (q.w - sMean[col + 3]) * inv;
  *(float4*)(xOut + base) = q;
}

extern "C" void kernel_launch(void* const* d_in, const int* in_sizes, int n_in,
                              void* d_out, int out_size, void* d_ws, size_t ws_size,
                              hipStream_t stream){
  (void)in_sizes; (void)n_in; (void)out_size;
  const float* x    = (const float*)d_in[0];
  const float* ea   = (const float*)d_in[1];
  const int*   eidx = (const int*)d_in[2];
  const float* ew1  = (const float*)d_in[3];
  const float* eb1  = (const float*)d_in[4];
  const float* ew2  = (const float*)d_in[5];
  const float* eb2  = (const float*)d_in[6];
  const float* ew3  = (const float*)d_in[7];
  const float* eb3  = (const float*)d_in[8];
  const float* eg   = (const float*)d_in[9];
  const float* ebt  = (const float*)d_in[10];
  const float* nw1  = (const float*)d_in[11];
  const float* nb1  = (const float*)d_in[12];
  const float* nw2  = (const float*)d_in[13];
  const float* nb2  = (const float*)d_in[14];
  const float* nw3  = (const float*)d_in[15];
  const float* nb3  = (const float*)d_in[16];
  const float* ng   = (const float*)d_in[17];
  const float* nbt  = (const float*)d_in[18];

  u16*   wt     = (u16*)d_ws;
  float* stats  = (float*)((char*)d_ws + 294912);
  int*   cnt    = (int*)((char*)d_ws + 297216);
  int*   off    = (int*)((char*)d_ws + 497408);
  int*   cursor = (int*)((char*)d_ws + 697600);
  int*   perm   = (int*)((char*)d_ws + 897792);
  int*   rank   = (int*)((char*)d_ws + 4097792);
  const bool useO = ws_size >= (7297792ull + (size_t)NE * 128 * 2);
  const bool useX = ws_size >= (7297792ull + (size_t)NE * 128 * 2 + (size_t)NN * 128 * 2);
  u16*   oBuf   = useO ? (u16*)((char*)d_ws + 7297792) : (u16*)nullptr;
  u16*   xB     = useX ? (u16*)((char*)d_ws + 7297792 + (size_t)NE * 128 * 2) : (u16*)nullptr;
  float* outX   = (float*)d_out;                 // Pab during edge, (fallback agg), then outX
  u16*   Pab    = (u16*)d_out;
  float* outE   = outX + (size_t)NN * 128;

  hipMemsetAsync((char*)d_ws + 294912, 0, 202496, stream);   // stats + cnt
  prep_kernel<<<3125, 256, 0, stream>>>(ew1, ew2, ew3, nw1, nw2, nw3, wt, x, xB, eidx, cnt, rank);
  scanpre_kernel<<<783, 256, 0, stream>>>(cnt, off, cursor, x, xB, wt, Pab);
  if (!useO) scatter_kernel<<<3125, 256, 0, stream>>>(eidx, cursor, perm);
  edge_kernel<<<6250, 512, 0, stream>>>(ea, eidx, wt, Pab, eb1, eb2, eb3, eg, ebt, off, rank, outE, oBuf);
  if (!useO) agg_f_kernel<<<12500, 256, 0, stream>>>(outE, ea, off, perm, outX);
  node_kernel<<<782, 256, 0, stream>>>(x, outX, oBuf, off, wt, nb1, nb2, nb3, ng, nbt, outX, stats);
  pairnorm_kernel<<<6250, 256, 0, stream>>>(outX, stats);
}

// Round 18
// 679.217 us; speedup vs baseline: 1.8337x; 1.8337x over previous
//
#include <hip/hip_runtime.h>
#include <hip/hip_bf16.h>

#define NN 50000
#define NE 800000
#define ROWB 272   // bytes per LDS tile row: 128 bf16 + 8 pad

typedef unsigned short u16;
typedef unsigned int u32;
typedef __attribute__((ext_vector_type(4))) float f32x4;
typedef __attribute__((ext_vector_type(8))) short short8;

// ws layout:
//   u16 wt[147456]   @0        : w1t(K=384) w2t@49152 w3t@65536 n1t@81920(K=256) n2t@114688 n3t@131072 ([n][k], bf16)
//   f32 stats[512]   @294912
//   int cnt[50000]   @297216
//   int off[50001]   @497408
//   int cursor[50000]@697600
//   int perm[800000] @897792   (fallback only)
//   int rank[800000] @4097792
//   u16 oBuf[NE*128] @7297792           (useO: ws >= 212.1 MB)
//   u16 xB[NN*128]   @212097792         (useX: ws >= 224.9 MB)
// d_out aliasing: Pab (u16[NN*256]) in outX slot during edge; node overwrites; pairnorm finalizes.

__device__ __forceinline__ u16 f2b(float f){ __hip_bfloat16 h = __float2bfloat16(f); u16 u; __builtin_memcpy(&u, &h, 2); return u; }
__device__ __forceinline__ float b2f(u16 u){ __hip_bfloat16 h; __builtin_memcpy(&h, &u, 2); return __bfloat162float(h); }
// silu via v_rcp_f32; ~1 ulp, fine for bf16 output
__device__ __forceinline__ float siluf(float v){
  const float e = __expf(-v);
  return v * __builtin_amdgcn_rcpf(1.f + e);
}

__device__ __forceinline__ uint4 cvt8(const float* __restrict__ s){
  const float4 a = *(const float4*)s;
  const float4 b = *(const float4*)(s + 4);
  union { u16 h[8]; uint4 q; } u;
  u.h[0]=f2b(a.x); u.h[1]=f2b(a.y); u.h[2]=f2b(a.z); u.h[3]=f2b(a.w);
  u.h[4]=f2b(b.x); u.h[5]=f2b(b.y); u.h[6]=f2b(b.z); u.h[7]=f2b(b.w);
  return u.q;
}

// 128-row tile, 8 waves: wm=wid>>2 (64 rows), wn=wid&3 (32 cols). acc[4][2].
template<int K>
__device__ __forceinline__ void gemm128(f32x4 acc[4][2], const u16* __restrict__ sA,
                                        const u16* __restrict__ wB, int wm, int wn, int lane){
  const int l15 = lane & 15, l4 = lane >> 4;
  const u16* w0 = wB + (size_t)(wn*32 + l15)*K + l4*8;
  const u16* w1 = w0 + (size_t)16*K;
  #pragma unroll
  for (int ks = 0; ks < 4; ++ks){
    const short8 b0 = *(const short8*)(w0 + ks*32);
    const short8 b1 = *(const short8*)(w1 + ks*32);
    const int kb = ks*64 + l4*16;
    short8 a[4];
    #pragma unroll
    for (int fr = 0; fr < 4; ++fr)
      a[fr] = *(const short8*)((const char*)sA + (wm*64 + fr*16 + l15)*ROWB + kb);
    #pragma unroll
    for (int fr = 0; fr < 4; ++fr){
      acc[fr][0] = __builtin_amdgcn_mfma_f32_16x16x32_bf16(a[fr], b0, acc[fr][0], 0, 0, 0);
      acc[fr][1] = __builtin_amdgcn_mfma_f32_16x16x32_bf16(a[fr], b1, acc[fr][1], 0, 0, 0);
    }
  }
}

// 64-row tile, 4 waves: wm=wid>>1 (32 rows), wn=wid&1 (64 cols). acc[2][4].
template<int K>
__device__ __forceinline__ void gemm64(f32x4 acc[2][4], const u16* __restrict__ sA,
                                       const u16* __restrict__ wB, int wm, int wn, int lane){
  const int l15 = lane & 15, l4 = lane >> 4;
  const u16* w0 = wB + (size_t)(wn*64 + l15)*K + l4*8;
  #pragma unroll
  for (int ks = 0; ks < 4; ++ks){
    short8 b[4];
    #pragma unroll
    for (int fc = 0; fc < 4; ++fc)
      b[fc] = *(const short8*)(w0 + (size_t)fc*16*K + ks*32);
    const int kb = ks*64 + l4*16;
    short8 a[2];
    #pragma unroll
    for (int fr = 0; fr < 2; ++fr)
      a[fr] = *(const short8*)((const char*)sA + (wm*32 + fr*16 + l15)*ROWB + kb);
    #pragma unroll
    for (int fr = 0; fr < 2; ++fr)
      #pragma unroll
      for (int fc = 0; fc < 4; ++fc)
        acc[fr][fc] = __builtin_amdgcn_mfma_f32_16x16x32_bf16(a[fr], b[fc], acc[fr][fc], 0, 0, 0);
  }
}

// acc + bias [+ SiLU] -> bf16 LDS tile (128-row/8-wave). C/D: col=lane&15, row=(lane>>4)*4+j.
__device__ __forceinline__ void epilogue(const f32x4 acc[4][2], const float* __restrict__ bias,
                                         u16* __restrict__ dst, int wm, int wn, int lane, bool doSilu){
  const int l15 = lane & 15, l4 = lane >> 4;
  #pragma unroll
  for (int fc = 0; fc < 2; ++fc){
    const int col = wn*32 + fc*16 + l15;
    const float bv = bias[col];
    #pragma unroll
    for (int fr = 0; fr < 4; ++fr){
      const int rbase = wm*64 + fr*16 + l4*4;
      #pragma unroll
      for (int j = 0; j < 4; ++j){
        float v = acc[fr][fc][j] + bv;
        if (doSilu) v = siluf(v);
        *(u16*)((char*)dst + (rbase + j)*ROWB + col*2) = f2b(v);
      }
    }
  }
}

// 64-row/4-wave variant
__device__ __forceinline__ void epilogue64(const f32x4 acc[2][4], const float* __restrict__ bias,
                                           u16* __restrict__ dst, int wm, int wn, int lane, bool doSilu){
  const int l15 = lane & 15, l4 = lane >> 4;
  #pragma unroll
  for (int fc = 0; fc < 4; ++fc){
    const int col = wn*64 + fc*16 + l15;
    const float bv = bias[col];
    #pragma unroll
    for (int fr = 0; fr < 2; ++fr){
      const int rbase = wm*32 + fr*16 + l4*4;
      #pragma unroll
      for (int j = 0; j < 4; ++j){
        float v = acc[fr][fc][j] + bv;
        if (doSilu) v = siluf(v);
        *(u16*)((char*)dst + (rbase + j)*ROWB + col*2) = f2b(v);
      }
    }
  }
}

// fused: weight transpose + x->bf16 conversion + receiver count (rank kept for slot assignment)
__global__ __launch_bounds__(256) void prep_kernel(const float* __restrict__ w1, const float* __restrict__ w2,
                                                   const float* __restrict__ w3, const float* __restrict__ m1,
                                                   const float* __restrict__ m2, const float* __restrict__ m3,
                                                   u16* __restrict__ wt,
                                                   const float* __restrict__ x, u16* __restrict__ xB,
                                                   const int* __restrict__ eidx, int* __restrict__ cnt,
                                                   int* __restrict__ rank){
  const int i = blockIdx.x * 256 + threadIdx.x;     // 0 .. 799999
  if (i < 147456){
    const float* src; int K, base, off;
    if      (i < 49152)  { src = w1; K = 384; base = 0;      off = i; }
    else if (i < 65536)  { src = w2; K = 128; base = 49152;  off = i - 49152; }
    else if (i < 81920)  { src = w3; K = 128; base = 65536;  off = i - 65536; }
    else if (i < 114688) { src = m1; K = 256; base = 81920;  off = i - 81920; }
    else if (i < 131072) { src = m2; K = 128; base = 114688; off = i - 114688; }
    else                 { src = m3; K = 128; base = 131072; off = i - 131072; }
    const int k = off >> 7, n = off & 127;
    wt[base + n*K + k] = f2b(src[off]);
  }
  if (xB){
    const size_t o = (size_t)i * 8;                 // NN*128/8 == NE exactly
    *(uint4*)(xB + o) = cvt8(x + o);
  }
  rank[i] = atomicAdd(&cnt[eidx[NE + i]], 1);
}

// fallback-only scatter (perm for agg_f)
__global__ __launch_bounds__(256) void scatter_kernel(const int* __restrict__ eidx, int* __restrict__ cursor,
                                                      int* __restrict__ perm){
  const int i = blockIdx.x * 256 + threadIdx.x;
  if (i < NE){
    const int pos = atomicAdd(&cursor[eidx[NE + i]], 1);
    perm[pos] = i;
  }
}

// ---------------- fused: block 0 = CSR scan; blocks 1..782 = Pab precompute ----------------
__global__ __launch_bounds__(256, 4) void scanpre_kernel(const int* __restrict__ cnt, int* __restrict__ off,
                                                         int* __restrict__ cursor,
                                                         const float* __restrict__ x, const u16* __restrict__ xB,
                                                         const u16* __restrict__ wt, u16* __restrict__ Pab){
  const int t = threadIdx.x;
  if (blockIdx.x == 0){
    __shared__ int s[256];
    const int CH = 196;                       // 256*196 = 50176 >= NN
    int sum = 0;
    for (int i = 0; i < CH; ++i){
      const int idx = t*CH + i;
      if (idx < NN) sum += cnt[idx];
    }
    s[t] = sum;
    __syncthreads();
    for (int d = 1; d < 256; d <<= 1){
      int v = (t >= d) ? s[t - d] : 0;
      __syncthreads();
      s[t] += v;
      __syncthreads();
    }
    int run = s[t] - sum;
    for (int i = 0; i < CH; ++i){
      const int idx = t*CH + i;
      if (idx < NN){
        off[idx] = run;
        cursor[idx] = run;
        run += cnt[idx];
        if (idx == NN - 1) off[NN] = run;
      }
    }
    return;
  }

  // ---- Pab precompute: Pab[n][0:128] = x@W1a, [128:256] = x@W1b ----
  __shared__ u16 sX[64*136];
  const int nBase = (blockIdx.x - 1) * 64;
  const int lane = t & 63, wid = t >> 6;
  const int wm = wid >> 1, wn = wid & 1;
  const int chunk = t & 15, r0 = t >> 4;

  #pragma unroll
  for (int p = 0; p < 4; ++p){
    const int row = r0 + p*16;
    const int node = nBase + row;
    uint4 v = {0u, 0u, 0u, 0u};
    if (node < NN){
      if (xB) v = *(const uint4*)(xB + (size_t)node*128 + chunk*8);
      else    v = cvt8(x + (size_t)node*128 + chunk*8);
    }
    *(uint4*)((char*)sX + row*ROWB + chunk*16) = v;
  }
  __syncthreads();

  const f32x4 z4 = {0.f, 0.f, 0.f, 0.f};
  const int l15 = lane & 15, l4 = lane >> 4;
  #pragma unroll
  for (int half = 0; half < 2; ++half){
    f32x4 acc[2][4];
    #pragma unroll
    for (int fr = 0; fr < 2; ++fr)
      #pragma unroll
      for (int fc = 0; fc < 4; ++fc) acc[fr][fc] = z4;
    gemm64<384>(acc, sX, wt + half*128, wm, wn, lane);   // W1a or W1b
    #pragma unroll
    for (int fc = 0; fc < 4; ++fc){
      const int col = wn*64 + fc*16 + l15;
      #pragma unroll
      for (int fr = 0; fr < 2; ++fr){
        const int rbase = wm*32 + fr*16 + l4*4;
        #pragma unroll
        for (int j = 0; j < 4; ++j){
          const int node = nBase + rbase + j;
          if (node < NN) Pab[(size_t)node*256 + half*128 + col] = f2b(acc[fr][fc][j]);
        }
      }
    }
  }
}

// ---------------- edge block: acc seeded from global Pab; slots = off[r]+rank[e] ----------------
__global__ __launch_bounds__(512, 4) void edge_kernel(
    const float* __restrict__ ea, const int* __restrict__ eidx,
    const u16* __restrict__ wt, const u16* __restrict__ Pab,
    const float* __restrict__ b1, const float* __restrict__ b2,
    const float* __restrict__ b3, const float* __restrict__ gma, const float* __restrict__ bta,
    const int* __restrict__ off, const int* __restrict__ rank,
    float* __restrict__ outE, u16* __restrict__ oBuf)
{
  __shared__ u16 sA[128*136];
  __shared__ float sMeta[640];
  __shared__ int sIdx[256];
  __shared__ int sSlot[128];
  const int t = threadIdx.x;
  const size_t eBase = (size_t)blockIdx.x * 128;

  if (t < 128){
    sIdx[t] = eidx[eBase + t];
    const int r = eidx[(size_t)NE + eBase + t];
    sIdx[t + 128] = r;
    sSlot[t] = oBuf ? (off[r] + rank[eBase + t]) : 0;
    sMeta[t]       = b1[t];
    sMeta[t + 128] = b2[t];
    sMeta[t + 256] = b3[t];
    sMeta[t + 384] = gma[t];
    sMeta[t + 512] = bta[t];
  }
  __syncthreads();

  const int lane = t & 63, wid = t >> 6;
  const int wm = wid >> 2, wn = wid & 3;
  const int chunk = t & 15, r0 = t >> 4;
  const int l15 = lane & 15, l4 = lane >> 4;

  // Stage ea -> sA (keep bf16 quads for the residual)
  uint4 eaQ[4];
  #pragma unroll
  for (int p = 0; p < 4; ++p){
    const int row = r0 + p*32;
    uint4 v = cvt8(ea + ((eBase + row)*128 + chunk*8));
    eaQ[p] = v;
    *(uint4*)((char*)sA + row*ROWB + chunk*16) = v;
  }

  // Seed acc directly from global Pab at this lane's C/D fragment coordinates.
  f32x4 acc[4][2];
  #pragma unroll
  for (int fr = 0; fr < 4; ++fr){
    #pragma unroll
    for (int j = 0; j < 4; ++j){
      const int row = wm*64 + fr*16 + l4*4 + j;
      const u16* pa = Pab + (size_t)sIdx[row]*256;
      const u16* pb = Pab + (size_t)sIdx[row + 128]*256 + 128;
      #pragma unroll
      for (int fc = 0; fc < 2; ++fc){
        const int col = wn*32 + fc*16 + l15;
        acc[fr][fc][j] = b2f(pa[col]) + b2f(pb[col]);
      }
    }
  }
  __syncthreads();

  gemm128<384>(acc, sA, wt + 256, wm, wn, lane);          // + ea @ W1c
  __syncthreads();
  epilogue(acc, sMeta + 0, sA, wm, wn, lane, true);       // h1 = silu(P + eaW1c + b1)
  __syncthreads();
  const f32x4 z4 = {0.f, 0.f, 0.f, 0.f};
  #pragma unroll
  for (int fr = 0; fr < 4; ++fr){ acc[fr][0] = z4; acc[fr][1] = z4; }
  gemm128<128>(acc, sA, wt + 49152, wm, wn, lane);        // h1 @ W2
  __syncthreads();
  epilogue(acc, sMeta + 128, sA, wm, wn, lane, true);     // h2
  __syncthreads();
  #pragma unroll
  for (int fr = 0; fr < 4; ++fr){ acc[fr][0] = z4; acc[fr][1] = z4; }
  gemm128<128>(acc, sA, wt + 65536, wm, wn, lane);        // h2 @ W3
  __syncthreads();
  epilogue(acc, sMeta + 256, sA, wm, wn, lane, false);    // h3
  __syncthreads();

  // LayerNorm over staging mapping: thread t owns rows {r0+32p}, cols [chunk*8, +8)
  {
    #pragma unroll
    for (int p = 0; p < 4; ++p){
      const int row = r0 + p*32;
      uint4 q = *(const uint4*)((const char*)sA + row*ROWB + chunk*16);
      const u16* pu = (const u16*)&q;
      float h[8];
      #pragma unroll
      for (int j = 0; j < 8; ++j) h[j] = b2f(pu[j]);
      float s = 0.f;
      #pragma unroll
      for (int j = 0; j < 8; ++j) s += h[j];
      s += __shfl_xor(s, 1); s += __shfl_xor(s, 2); s += __shfl_xor(s, 4); s += __shfl_xor(s, 8);
      const float mu = s * (1.f/128.f);
      float ss = 0.f;
      #pragma unroll
      for (int j = 0; j < 8; ++j){ const float d = h[j] - mu; ss += d*d; }
      ss += __shfl_xor(ss, 1); ss += __shfl_xor(ss, 2); ss += __shfl_xor(ss, 4); ss += __shfl_xor(ss, 8);
      const float rs = rsqrtf(fmaxf(ss*(1.f/128.f), 0.f) + 1e-5f);
      const size_t e = eBase + row;
      const u16* ep = (const u16*)&eaQ[p];
      alignas(16) float orow[8];
      alignas(16) u16 obf[8];
      #pragma unroll
      for (int j = 0; j < 8; ++j){
        const int col = chunk*8 + j;
        const float o = sMeta[384 + col]*(h[j] - mu)*rs + sMeta[512 + col];
        orow[j] = b2f(ep[j]) + o;
        obf[j] = f2b(o);
      }
      float* dst = outE + e*128 + chunk*8;
      *(float4*)dst       = ((const float4*)orow)[0];
      *(float4*)(dst + 4) = ((const float4*)orow)[1];
      if (oBuf) *(uint4*)(oBuf + (size_t)sSlot[row]*128 + chunk*8) = *(const uint4*)obf;
    }
  }
}

// ---------------- fallback aggregation (only when oBuf unavailable) ----------------
__global__ __launch_bounds__(256) void agg_f_kernel(const float* __restrict__ outE, const float* __restrict__ ea,
                                                    const int* __restrict__ off, const int* __restrict__ perm,
                                                    float* __restrict__ agg){
  const int node = blockIdx.x * 4 + (threadIdx.x >> 6);
  const int lane = threadIdx.x & 63;
  if (node >= NN) return;
  const int s = off[node], e = off[node + 1];
  float a0 = 0.f, a1 = 0.f;
  for (int i = s; i < e; ++i){
    const size_t r = (size_t)perm[i] * 128;
    a0 += outE[r + lane]      - ea[r + lane];
    a1 += outE[r + 64 + lane] - ea[r + 64 + lane];
  }
  agg[(size_t)node*128 + lane]      = a0;
  agg[(size_t)node*128 + 64 + lane] = a1;
}

// ---------------- node block: 64 nodes, 4 waves, fused CSR aggregation ----------------
__global__ __launch_bounds__(256, 4) void node_kernel(
    const float* __restrict__ x, const float* __restrict__ aggF,
    const u16* __restrict__ oBuf, const int* __restrict__ off,
    const u16* __restrict__ wt,
    const float* __restrict__ b1, const float* __restrict__ b2, const float* __restrict__ b3,
    const float* __restrict__ gma, const float* __restrict__ bta,
    float* __restrict__ outX, float* __restrict__ stats)
{
  __shared__ u16 sA[64*136];
  __shared__ float sMeta[640];
  __shared__ float sCol[128];
  __shared__ float sSq;
  const int t = threadIdx.x;
  const int nBase = blockIdx.x * 64;

  if (t < 128){
    sMeta[t]       = b1[t];
    sMeta[t + 128] = b2[t];
    sMeta[t + 256] = b3[t];
    sMeta[t + 384] = gma[t];
    sMeta[t + 512] = bta[t];
    sCol[t] = 0.f;
  }
  if (t == 0) sSq = 0.f;
  __syncthreads();

  const int lane = t & 63, wid = t >> 6;
  const int wm = wid >> 1, wn = wid & 1;
  const int chunk = t & 15, r0 = t >> 4;

  const f32x4 z4 = {0.f, 0.f, 0.f, 0.f};
  f32x4 acc[2][4];
  #pragma unroll
  for (int fr = 0; fr < 2; ++fr)
    #pragma unroll
    for (int fc = 0; fc < 4; ++fc) acc[fr][fc] = z4;

  for (int kc = 0; kc < 2; ++kc){
    #pragma unroll
    for (int p = 0; p < 4; ++p){
      const int row = r0 + p*16;
      const int node = nBase + row;
      uint4 v = {0u, 0u, 0u, 0u};
      if (node < NN){
        if (kc == 0){
          v = cvt8(x + (size_t)node*128 + chunk*8);
        } else if (oBuf){
          float a[8] = {0.f,0.f,0.f,0.f,0.f,0.f,0.f,0.f};
          const int s0 = off[node], e0 = off[node + 1];
          for (int i = s0; i < e0; ++i){
            uint4 q = *(const uint4*)(oBuf + (size_t)i*128 + chunk*8);
            const u16* pu = (const u16*)&q;
            #pragma unroll
            for (int j = 0; j < 8; ++j) a[j] += b2f(pu[j]);
          }
          union { u16 h[8]; uint4 q; } u;
          #pragma unroll
          for (int j = 0; j < 8; ++j) u.h[j] = f2b(a[j]);
          v = u.q;
        } else {
          v = cvt8(aggF + (size_t)node*128 + chunk*8);
        }
      }
      *(uint4*)((char*)sA + row*ROWB + chunk*16) = v;
    }
    __syncthreads();
    gemm64<256>(acc, sA, wt + 81920 + kc*128, wm, wn, lane);
    __syncthreads();
  }
  epilogue64(acc, sMeta + 0, sA, wm, wn, lane, true);
  __syncthreads();
  #pragma unroll
  for (int fr = 0; fr < 2; ++fr)
    #pragma unroll
    for (int fc = 0; fc < 4; ++fc) acc[fr][fc] = z4;
  gemm64<128>(acc, sA, wt + 114688, wm, wn, lane);
  __syncthreads();
  epilogue64(acc, sMeta + 128, sA, wm, wn, lane, true);
  __syncthreads();
  #pragma unroll
  for (int fr = 0; fr < 2; ++fr)
    #pragma unroll
    for (int fc = 0; fc < 4; ++fc) acc[fr][fc] = z4;
  gemm64<128>(acc, sA, wt + 131072, wm, wn, lane);
  __syncthreads();
  epilogue64(acc, sMeta + 256, sA, wm, wn, lane, false);
  __syncthreads();

  // LN + residual + pairnorm stats over staging mapping (rows r0+16p, cols chunk*8..+8)
  {
    float lssq = 0.f;
    #pragma unroll
    for (int p = 0; p < 4; ++p){
      const int row = r0 + p*16;
      const int node = nBase + row;
      uint4 q = *(const uint4*)((const char*)sA + row*ROWB + chunk*16);
      const u16* pu = (const u16*)&q;
      float h[8];
      #pragma unroll
      for (int j = 0; j < 8; ++j) h[j] = b2f(pu[j]);
      float s = 0.f;
      #pragma unroll
      for (int j = 0; j < 8; ++j) s += h[j];
      s += __shfl_xor(s, 1); s += __shfl_xor(s, 2); s += __shfl_xor(s, 4); s += __shfl_xor(s, 8);
      const float mu = s * (1.f/128.f);
      float ss = 0.f;
      #pragma unroll
      for (int j = 0; j < 8; ++j){ const float d = h[j] - mu; ss += d*d; }
      ss += __shfl_xor(ss, 1); ss += __shfl_xor(ss, 2); ss += __shfl_xor(ss, 4); ss += __shfl_xor(ss, 8);
      const float rs = rsqrtf(fmaxf(ss*(1.f/128.f), 0.f) + 1e-5f);
      if (node < NN){
        const float* xRow = x + (size_t)node*128 + chunk*8;
        const float4 xa = *(const float4*)xRow;
        const float4 xb = *(const float4*)(xRow + 4);
        float xr[8] = {xa.x, xa.y, xa.z, xa.w, xb.x, xb.y, xb.z, xb.w};
        alignas(16) float orow[8];
        #pragma unroll
        for (int j = 0; j < 8; ++j){
          const int col = chunk*8 + j;
          const float o = sMeta[384 + col]*(h[j] - mu)*rs + sMeta[512 + col];
          const float res = xr[j] + o;   // RESIDUAL_SCALE = 1
          orow[j] = res;
          atomicAdd(&sCol[col], res);
          lssq += res*res;
        }
        float* dst = outX + (size_t)node*128 + chunk*8;
        *(float4*)dst       = ((const float4*)orow)[0];
        *(float4*)(dst + 4) = ((const float4*)orow)[1];
      }
    }
    #pragma unroll
    for (int m = 1; m < 64; m <<= 1) lssq += __shfl_xor(lssq, m);
    if (lane == 0) atomicAdd(&sSq, lssq);
  }
  __syncthreads();
  if (t < 128) atomicAdd(&stats[t], sCol[t]);
  if (t == 0)  atomicAdd(&stats[128], sSq);
}

// ---------------- pairnorm (finalize fused) ----------------
__global__ __launch_bounds__(256) void pairnorm_kernel(float* __restrict__ xOut, const float* __restrict__ stats){
  __shared__ float sMean[128];
  __shared__ float sP2[2];
  __shared__ float sInv;
  const int t = threadIdx.x;
  float m2 = 0.f;
  if (t < 128){
    const float mean = stats[t] * (1.f / (float)NN);
    sMean[t] = mean;
    m2 = mean * mean;
  }
  #pragma unroll
  for (int m = 1; m < 64; m <<= 1) m2 += __shfl_xor(m2, m);
  if ((t & 63) == 0 && t < 128) sP2[t >> 6] = m2;
  __syncthreads();
  if (t == 0){
    float ssc = stats[128] - (float)NN * (sP2[0] + sP2[1]);
    ssc = fmaxf(ssc, 0.f);
    const float rms = sqrtf(ssc * (1.f / (float)NN)) + 1e-8f;
    sInv = 1.f / rms;
  }
  __syncthreads();
  const size_t base = ((size_t)blockIdx.x * 256 + t) * 4;
  const int col = (int)(base & 127);
  float4 q = *(float4*)(xOut + base);
  const float inv = sInv;
  q.x = (q.x - sMean[col])     * inv;
  q.y = (q.y - sMean[col + 1]) * inv;
  q.z = (q.z - sMean[col + 2]) * inv;
  q.w = (q.w - sMean[col + 3]) * inv;
  *(float4*)(xOut + base) = q;
}

extern "C" void kernel_launch(void* const* d_in, const int* in_sizes, int n_in,
                              void* d_out, int out_size, void* d_ws, size_t ws_size,
                              hipStream_t stream){
  (void)in_sizes; (void)n_in; (void)out_size;
  const float* x    = (const float*)d_in[0];
  const float* ea   = (const float*)d_in[1];
  const int*   eidx = (const int*)d_in[2];
  const float* ew1  = (const float*)d_in[3];
  const float* eb1  = (const float*)d_in[4];
  const float* ew2  = (const float*)d_in[5];
  const float* eb2  = (const float*)d_in[6];
  const float* ew3  = (const float*)d_in[7];
  const float* eb3  = (const float*)d_in[8];
  const float* eg   = (const float*)d_in[9];
  const float* ebt  = (const float*)d_in[10];
  const float* nw1  = (const float*)d_in[11];
  const float* nb1  = (const float*)d_in[12];
  const float* nw2  = (const float*)d_in[13];
  const float* nb2  = (const float*)d_in[14];
  const float* nw3  = (const float*)d_in[15];
  const float* nb3  = (const float*)d_in[16];
  const float* ng   = (const float*)d_in[17];
  const float* nbt  = (const float*)d_in[18];

  u16*   wt     = (u16*)d_ws;
  float* stats  = (float*)((char*)d_ws + 294912);
  int*   cnt    = (int*)((char*)d_ws + 297216);
  int*   off    = (int*)((char*)d_ws + 497408);
  int*   cursor = (int*)((char*)d_ws + 697600);
  int*   perm   = (int*)((char*)d_ws + 897792);
  int*   rank   = (int*)((char*)d_ws + 4097792);
  const bool useO = ws_size >= (7297792ull + (size_t)NE * 128 * 2);
  const bool useX = ws_size >= (7297792ull + (size_t)NE * 128 * 2 + (size_t)NN * 128 * 2);
  u16*   oBuf   = useO ? (u16*)((char*)d_ws + 7297792) : (u16*)nullptr;
  u16*   xB     = useX ? (u16*)((char*)d_ws + 7297792 + (size_t)NE * 128 * 2) : (u16*)nullptr;
  float* outX   = (float*)d_out;                 // Pab during edge, (fallback agg), then outX
  u16*   Pab    = (u16*)d_out;
  float* outE   = outX + (size_t)NN * 128;

  hipMemsetAsync((char*)d_ws + 294912, 0, 202496, stream);   // stats + cnt
  prep_kernel<<<3125, 256, 0, stream>>>(ew1, ew2, ew3, nw1, nw2, nw3, wt, x, xB, eidx, cnt, rank);
  scanpre_kernel<<<783, 256, 0, stream>>>(cnt, off, cursor, x, xB, wt, Pab);
  if (!useO) scatter_kernel<<<3125, 256, 0, stream>>>(eidx, cursor, perm);
  edge_kernel<<<6250, 512, 0, stream>>>(ea, eidx, wt, Pab, eb1, eb2, eb3, eg, ebt, off, rank, outE, oBuf);
  if (!useO) agg_f_kernel<<<12500, 256, 0, stream>>>(outE, ea, off, perm, outX);
  node_kernel<<<782, 256, 0, stream>>>(x, outX, oBuf, off, wt, nb1, nb2, nb3, ng, nbt, outX, stats);
  pairnorm_kernel<<<6250, 256, 0, stream>>>(outX, stats);
}